// Round 1
// baseline (984.622 us; speedup 1.0000x reference)
//
#include <hip/hip_runtime.h>

#define SEQ 512
#define BATCH 256
#define INDIM 256
#define MLP 128
#define M_ROWS (SEQ * BATCH)        // 131072
#define PRE_STRIDE 136              // 128 mlp-pre + 4 gate-pre + 4 pad
#define AUX_OFF ((size_t)M_ROWS * PRE_STRIDE)  // in floats

// ---------------------------------------------------------------------------
// Kernel 1: prep — column sums of the recurrent halves of W1 and gate weights.
// ---------------------------------------------------------------------------
__global__ __launch_bounds__(256) void prep_kernel(
    const float* __restrict__ W1,
    const float* __restrict__ Wf, const float* __restrict__ Wi,
    const float* __restrict__ Wg, const float* __restrict__ Wo,
    const float* __restrict__ bf, const float* __restrict__ bi,
    const float* __restrict__ bg, const float* __restrict__ bo,
    float* __restrict__ aux) {
  const int tid = threadIdx.x;
  if (tid < 128) {
    float s = 0.f;
    for (int k = 0; k < 256; ++k) s += W1[(size_t)(256 + k) * 128 + tid];
    aux[tid] = s;
  } else if (tid < 132) {
    const int g = tid - 128;
    const float* w = (g == 0) ? Wf : (g == 1) ? Wi : (g == 2) ? Wg : Wo;
    float s = 0.f;
    for (int k = 0; k < 256; ++k) s += w[256 + k];
    aux[128 + g] = s;
  } else if (tid < 136) {
    const int g = tid - 132;
    const float* bp = (g == 0) ? bf : (g == 1) ? bi : (g == 2) ? bg : bo;
    aux[132 + g] = bp[0];
  }
}

// ---------------------------------------------------------------------------
// Kernel 2: big fp32 GEMM — R5 version verbatim (proven ~306 µs).
// ---------------------------------------------------------------------------
#define BK 16
#define LDX 132  // padded LDS row stride (words)

__global__ __launch_bounds__(256) void gemm_kernel(
    const float* __restrict__ X,    // [M_ROWS][256]
    const float* __restrict__ W1,   // [512][128] (only rows 0..255 used here)
    const float* __restrict__ b1p,  // [128]
    const float* __restrict__ Wf, const float* __restrict__ Wi,
    const float* __restrict__ Wg, const float* __restrict__ Wo,
    const float* __restrict__ bfp, const float* __restrict__ bip,
    const float* __restrict__ bgp, const float* __restrict__ bop,
    float* __restrict__ PRE) {
  __shared__ __align__(16) float Xs[BK * LDX];   // [kk][row], row-padded
  __shared__ __align__(16) float Ws[BK * LDX];   // [kk][col]
  __shared__ float Wgs[BK * 4];                  // [kk][gate]

  const int tid = threadIdx.x;
  const int blk = blockIdx.x;
  const int tx = tid & 15, ty = tid >> 4;       // 16x16 thread grid
  const int r_st = tid >> 1, kh = (tid & 1) * 8; // X staging role
  const int wk = tid >> 4, wn = (tid & 15) * 8;  // W staging role
  const int r2 = tid >> 1, gp = (tid & 1) * 2;   // gate compute role

  const size_t rowbase = (size_t)blk * 128;

  float acc[8][8] = {};
  float ga = 0.f, gb = 0.f;

  for (int kc = 0; kc < 256; kc += BK) {
    const float4 xa = *(const float4*)&X[(rowbase + r_st) * 256 + kc + kh];
    const float4 xb = *(const float4*)&X[(rowbase + r_st) * 256 + kc + kh + 4];
    const float4 wa = *(const float4*)&W1[(size_t)(kc + wk) * 128 + wn];
    const float4 wb = *(const float4*)&W1[(size_t)(kc + wk) * 128 + wn + 4];
    float wgv = 0.f;
    if (tid < 64) {
      const int kk = tid >> 2, g = tid & 3;
      const float* w = (g == 0) ? Wf : (g == 1) ? Wi : (g == 2) ? Wg : Wo;
      wgv = w[kc + kk];
    }
    __syncthreads();
    Xs[(kh + 0) * LDX + r_st] = xa.x;
    Xs[(kh + 1) * LDX + r_st] = xa.y;
    Xs[(kh + 2) * LDX + r_st] = xa.z;
    Xs[(kh + 3) * LDX + r_st] = xa.w;
    Xs[(kh + 4) * LDX + r_st] = xb.x;
    Xs[(kh + 5) * LDX + r_st] = xb.y;
    Xs[(kh + 6) * LDX + r_st] = xb.z;
    Xs[(kh + 7) * LDX + r_st] = xb.w;
    *(float4*)&Ws[wk * LDX + wn] = wa;
    *(float4*)&Ws[wk * LDX + wn + 4] = wb;
    if (tid < 64) Wgs[tid] = wgv;
    __syncthreads();

#pragma unroll
    for (int kk = 0; kk < BK; ++kk) {
      const float4 a0 = *(const float4*)&Xs[kk * LDX + ty * 8];
      const float4 a1 = *(const float4*)&Xs[kk * LDX + ty * 8 + 4];
      const float4 c0 = *(const float4*)&Ws[kk * LDX + tx * 8];
      const float4 c1 = *(const float4*)&Ws[kk * LDX + tx * 8 + 4];
      const float av[8] = {a0.x, a0.y, a0.z, a0.w, a1.x, a1.y, a1.z, a1.w};
      const float bv[8] = {c0.x, c0.y, c0.z, c0.w, c1.x, c1.y, c1.z, c1.w};
#pragma unroll
      for (int i = 0; i < 8; ++i)
#pragma unroll
        for (int j = 0; j < 8; ++j)
          acc[i][j] = fmaf(av[i], bv[j], acc[i][j]);
      const float xv = Xs[kk * LDX + r2];
      ga = fmaf(xv, Wgs[kk * 4 + gp], ga);
      gb = fmaf(xv, Wgs[kk * 4 + gp + 1], gb);
    }
  }

  float bias[8];
  {
    const float4 u0 = *(const float4*)&b1p[tx * 8];
    const float4 u1 = *(const float4*)&b1p[tx * 8 + 4];
    bias[0] = u0.x; bias[1] = u0.y; bias[2] = u0.z; bias[3] = u0.w;
    bias[4] = u1.x; bias[5] = u1.y; bias[6] = u1.z; bias[7] = u1.w;
  }
#pragma unroll
  for (int i = 0; i < 8; ++i) {
    const size_t row = rowbase + ty * 8 + i;
    float4 o0, o1;
    o0.x = acc[i][0] + bias[0]; o0.y = acc[i][1] + bias[1];
    o0.z = acc[i][2] + bias[2]; o0.w = acc[i][3] + bias[3];
    o1.x = acc[i][4] + bias[4]; o1.y = acc[i][5] + bias[5];
    o1.z = acc[i][6] + bias[6]; o1.w = acc[i][7] + bias[7];
    *(float4*)&PRE[row * PRE_STRIDE + tx * 8] = o0;
    *(float4*)&PRE[row * PRE_STRIDE + tx * 8 + 4] = o1;
  }
  {
    const float ab = (gp == 0) ? bfp[0] : bgp[0];
    const float bb2 = (gp == 0) ? bip[0] : bop[0];
    float2 og;
    og.x = ga + ab; og.y = gb + bb2;
    *(float2*)&PRE[(rowbase + r2) * PRE_STRIDE + 128 + gp] = og;
  }
}

// ---------------------------------------------------------------------------
// Kernel 3 (R8 redesign): serial recurrence with NO memory on the h-chain.
//
// Old structure: h -> h1 -> LDS write -> 16x ds_read -> matvec. The write+read
// latency plus 33 DS ops/step and fragile register prefetch gave ~2090 cy/step
// (VALUBusy 12.5%). New structure:
//  - PRE rows staged into LDS by global_load_lds (size=16, one op/row),
//    depth-4 pipeline over 8 slots with hand-counted s_waitcnt vmcnt(7)
//    (never drained to 0 in steady state). Staging is h-independent.
//  - s1 (W1 recurrent col-sums) lives in a static LDS copy; each lane of a
//    half reads the same addresses -> LDS broadcast, conflict-free.
//  - Each lane redundantly computes h1 for its K-half fused into the dot:
//    x = relu(fma(h, s1_j, pre_j)); q = fma(x, w2r_j, q). +128 VALU ops/lane
//    but the only h-dependent memory op left in the step is nothing at all.
//  - Cross-lane tail shrinks: 1 shfl_xor(32) + 1 cos/lane + 8-shfl gather
//    (was 16 shfl + 8 cos/lane). Product-sum chain kept in the exact old
//    order for bit-stable numerics (absmax was near threshold).
// VM-op ledger per body t: [wait][stage(t+4)][...][store(t)]. Ops newer than
// stage(t) at the wait: 3 stages + 4 stores = 7 -> vmcnt(7). t<4: vmcnt(0)
// (robust against compiler sinking prologue loads; costs <1 us once).
// ---------------------------------------------------------------------------
__device__ __forceinline__ float sigmoid_f(float x) {
  return __fdividef(1.0f, 1.0f + __expf(-x));
}
__device__ __forceinline__ float tanh_f(float x) {
  const float e = __expf(-2.0f * x);
  return __fdividef(1.0f - e, 1.0f + e);
}
__device__ __forceinline__ float readlane_f(float v, int lane) {
  return __int_as_float(__builtin_amdgcn_readlane(__float_as_int(v), lane));
}

#define GLOBAL_AS __attribute__((address_space(1)))
#define LDS_AS __attribute__((address_space(3)))

__device__ __forceinline__ void stage_row16(const float* grow, float* lslot,
                                            int lane) {
  // 64 lanes x 16 B = 1024 B: stages floats 0..255 of the row (132 valid;
  // over-read lands in the next PRE row / aux region — always allocated).
  __builtin_amdgcn_global_load_lds((const GLOBAL_AS void*)(grow + 4 * lane),
                                   (LDS_AS void*)lslot, 16, 0, 0);
}

__global__ __attribute__((amdgpu_waves_per_eu(1, 1))) __launch_bounds__(64)
void rec_kernel(
    const float* __restrict__ PRE, const float* __restrict__ W2,
    const float* __restrict__ b2, const float* __restrict__ aux,
    float* __restrict__ out) {
  __shared__ __align__(16) float pstage[8 * 256];  // 8 slots x 1 KB
  __shared__ __align__(16) float s1s[128];

  const int l = threadIdx.x;
  const int b = blockIdx.x;
  const int m = l & 31, half = l >> 5;
  const int g = m >> 3;             // my gate: 0=f 1=i 2=g 3=o
  const int g8 = g * 8;

  // W2 fragment: lane (m,half) holds W2[half*64+u][m], u=0..63 (64 VGPRs).
  float w2r[64];
#pragma unroll
  for (int u = 0; u < 64; ++u) w2r[u] = W2[(size_t)(half * 64 + u) * 32 + m];
  const float b2m = b2[m];
  const float4 sg = *(const float4*)&aux[128];  // sf, si, sg, so

  // s1 -> LDS (broadcast source for the fused relu-matvec).
  *(float2*)&s1s[2 * l] = *(const float2*)&aux[2 * l];

  const float* pr0 = PRE + (size_t)b * PRE_STRIDE;
  const size_t ts = (size_t)BATCH * PRE_STRIDE;

  // Prologue: stage rows 0..3 into slots 0..3.
#pragma unroll
  for (int k = 0; k < 4; ++k)
    stage_row16(pr0 + (size_t)k * ts, &pstage[k * 256], l);

  float h = 0.f, c = 0.f;

  for (int t = 0; t < SEQ; ++t) {
    if (t < 4) {
      asm volatile("s_waitcnt vmcnt(0)" ::: "memory");
    } else {
      asm volatile("s_waitcnt vmcnt(7)" ::: "memory");
    }
    __builtin_amdgcn_sched_barrier(0);

    // Issue next stage immediately (slot (t+4)&7 is never the one being read;
    // row index clamped at the tail — those slots are never consumed).
    {
      const int tn = (t + 4 < SEQ) ? (t + 4) : (SEQ - 1);
      stage_row16(pr0 + (size_t)tn * ts, &pstage[((t + 4) & 7) * 256], l);
    }

    const float* slot = &pstage[(t & 7) * 256];

    // Gate pre-activations (uniform b128 read) + classical gates — VALU work
    // the scheduler can overlap with the matvec DS stream below.
    const float4 gpre = *(const float4*)&slot[128];
    const float zf = fmaf(h, sg.x, gpre.x);
    const float zi = fmaf(h, sg.y, gpre.y);
    const float zg = fmaf(h, sg.z, gpre.z);
    const float zo = fmaf(h, sg.w, gpre.w);
    const float cf = sigmoid_f(zf);
    const float ci = sigmoid_f(zi);
    const float cg = tanh_f(zg);
    const float co = sigmoid_f(zo);

    // Fused redundant-h1 matvec over this lane's K-half (identical fp ops to
    // the old kernel: fmaf(h,s1,pre) -> max -> fmaf into q0..q3 by e-slot).
    const float* ps = slot + half * 64;
    const float* ss = s1s + half * 64;
    float q0 = 0.f, q1 = 0.f, q2 = 0.f, q3 = 0.f;
#pragma unroll
    for (int j = 0; j < 16; ++j) {
      const float4 pv = *(const float4*)&ps[4 * j];
      const float4 sv = *(const float4*)&ss[4 * j];
      const float x0 = fmaxf(fmaf(h, sv.x, pv.x), 0.f);
      const float x1 = fmaxf(fmaf(h, sv.y, pv.y), 0.f);
      const float x2 = fmaxf(fmaf(h, sv.z, pv.z), 0.f);
      const float x3 = fmaxf(fmaf(h, sv.w, pv.w), 0.f);
      q0 = fmaf(x0, w2r[4 * j + 0], q0);
      q1 = fmaf(x1, w2r[4 * j + 1], q1);
      q2 = fmaf(x2, w2r[4 * j + 2], q2);
      q3 = fmaf(x3, w2r[4 * j + 3], q3);
    }
    float part = (q0 + q1) + (q2 + q3);
    part += __shfl_xor(part, 32, 64);          // both halves now hold a+b

    const float cm = __cosf(part + b2m);       // one cos per lane (my column)
    const int sb = (l & 32) + g8;              // gather within my own half
    const float e0 = __shfl(cm, sb + 0, 64);
    const float e1 = __shfl(cm, sb + 1, 64);
    const float e2 = __shfl(cm, sb + 2, 64);
    const float e3 = __shfl(cm, sb + 3, 64);
    const float e4 = __shfl(cm, sb + 4, 64);
    const float e5 = __shfl(cm, sb + 5, 64);
    const float e6 = __shfl(cm, sb + 6, 64);
    const float e7 = __shfl(cm, sb + 7, 64);
    float p = e0, s = e0;                      // exact old summation order
    p *= e1; s += p;
    p *= e2; s += p;
    p *= e3; s += p;
    p *= e4; s += p;
    p *= e5; s += p;
    p *= e6; s += p;
    p *= e7; s += p;
    const float qv = s * 0.125f;

    const float qarg = (g == 2) ? (2.0f * qv) : qv;
    const float qs = sigmoid_f(qarg);
    const float av = (g == 2) ? (2.0f * qs - 1.0f) : qs;

    const float aF = readlane_f(av, 0);
    const float aI = readlane_f(av, 8);
    const float aG = readlane_f(av, 16);
    const float aO = readlane_f(av, 24);

    const float f  = 0.5f * (cf + aF);
    const float ii = 0.5f * (ci + aI);
    const float gg = 0.5f * (cg + aG);
    const float oo = 0.5f * (co + aO);

    c = fmaf(f, c, ii * gg);
    h = oo * tanh_f(c);

    float4 hv4; hv4.x = h; hv4.y = h; hv4.z = h; hv4.w = h;
    *(float4*)(out + ((size_t)t * BATCH + b) * 256 + 4 * l) = hv4;
  }

  // final (hx, cx)
  float4 hq; hq.x = h; hq.y = h; hq.z = h; hq.w = h;
  float4 cq; cq.x = c; cq.y = c; cq.z = c; cq.w = c;
  *(float4*)(out + (size_t)SEQ * BATCH * 256 + (size_t)b * 256 + 4 * l) = hq;
  *(float4*)(out + (size_t)SEQ * BATCH * 256 + (size_t)BATCH * 256 +
             (size_t)b * 256 + 4 * l) = cq;
}

// ---------------------------------------------------------------------------
extern "C" void kernel_launch(void* const* d_in, const int* in_sizes, int n_in,
                              void* d_out, int out_size, void* d_ws,
                              size_t ws_size, hipStream_t stream) {
  const float* X  = (const float*)d_in[0];
  const float* W1 = (const float*)d_in[1];
  const float* b1 = (const float*)d_in[2];
  const float* W2 = (const float*)d_in[3];
  const float* b2 = (const float*)d_in[4];
  const float* Wf = (const float*)d_in[5];
  const float* bf = (const float*)d_in[6];
  const float* Wi = (const float*)d_in[7];
  const float* bi = (const float*)d_in[8];
  const float* Wg = (const float*)d_in[9];
  const float* bg = (const float*)d_in[10];
  const float* Wo = (const float*)d_in[11];
  const float* bo = (const float*)d_in[12];

  float* ws  = (float*)d_ws;
  float* PRE = ws;
  float* aux = ws + AUX_OFF;
  float* out = (float*)d_out;

  prep_kernel<<<1, 256, 0, stream>>>(W1, Wf, Wi, Wg, Wo, bf, bi, bg, bo, aux);
  gemm_kernel<<<M_ROWS / 128, 256, 0, stream>>>(X, W1, b1, Wf, Wi, Wg, Wo,
                                                bf, bi, bg, bo, PRE);
  rec_kernel<<<BATCH, 64, 0, stream>>>(PRE, W2, b2, aux, out);
}

// Round 3
// 879.965 us; speedup vs baseline: 1.1189x; 1.1189x over previous
//
#include <hip/hip_runtime.h>

#define SEQ 512
#define BATCH 256
#define INDIM 256
#define MLP 128
#define M_ROWS (SEQ * BATCH)        // 131072
#define PRE_STRIDE 136              // 128 mlp-pre + 4 gate-pre + 4 pad
#define AUX_OFF ((size_t)M_ROWS * PRE_STRIDE)  // in floats

// ---------------------------------------------------------------------------
// Kernel 1: prep — column sums of the recurrent halves of W1 and gate weights.
// ---------------------------------------------------------------------------
__global__ __launch_bounds__(256) void prep_kernel(
    const float* __restrict__ W1,
    const float* __restrict__ Wf, const float* __restrict__ Wi,
    const float* __restrict__ Wg, const float* __restrict__ Wo,
    const float* __restrict__ bf, const float* __restrict__ bi,
    const float* __restrict__ bg, const float* __restrict__ bo,
    float* __restrict__ aux) {
  const int tid = threadIdx.x;
  if (tid < 128) {
    float s = 0.f;
    for (int k = 0; k < 256; ++k) s += W1[(size_t)(256 + k) * 128 + tid];
    aux[tid] = s;
  } else if (tid < 132) {
    const int g = tid - 128;
    const float* w = (g == 0) ? Wf : (g == 1) ? Wi : (g == 2) ? Wg : Wo;
    float s = 0.f;
    for (int k = 0; k < 256; ++k) s += w[256 + k];
    aux[128 + g] = s;
  } else if (tid < 136) {
    const int g = tid - 132;
    const float* bp = (g == 0) ? bf : (g == 1) ? bi : (g == 2) ? bg : bo;
    aux[132 + g] = bp[0];
  }
}

// ---------------------------------------------------------------------------
// Kernel 2: big fp32 GEMM — R9: software-pipelined staging + reg-sourced gate.
//  R5 baseline exposed global-load latency 16x/block (loads issued at chunk
//  top, consumed right across a barrier). Now: prefetch chunk k+1 into regs
//  AFTER the write-barrier of chunk k, so ~600-900 cy of VMEM latency hides
//  under the ~2000 cy 16-kk compute. Gate dot's xv read (ds_read_b32 per kk)
//  replaced by av[tx>>1] — the same float already in registers (gate rows
//  remapped to each thread's own 8-row tile; identical values, identical fma
//  order -> bitwise-identical PRE). launch_bounds(256,3): VGPR cap ~170,
//  guarantees >=3 blocks/CU (R7 lesson: occupancy is the binding constraint).
// ---------------------------------------------------------------------------
#define BK 16
#define LDX 132  // padded LDS row stride (words)

__global__ __launch_bounds__(256, 3) void gemm_kernel(
    const float* __restrict__ X,    // [M_ROWS][256]
    const float* __restrict__ W1,   // [512][128] (only rows 0..255 used here)
    const float* __restrict__ b1p,  // [128]
    const float* __restrict__ Wf, const float* __restrict__ Wi,
    const float* __restrict__ Wg, const float* __restrict__ Wo,
    const float* __restrict__ bfp, const float* __restrict__ bip,
    const float* __restrict__ bgp, const float* __restrict__ bop,
    float* __restrict__ PRE) {
  __shared__ __align__(16) float Xs[BK * LDX];   // [kk][row], row-padded
  __shared__ __align__(16) float Ws[BK * LDX];   // [kk][col]
  __shared__ float Wgs[BK * 4];                  // [kk][gate]

  const int tid = threadIdx.x;
  const int blk = blockIdx.x;
  const int tx = tid & 15, ty = tid >> 4;        // 16x16 thread grid
  const int r_st = tid >> 1, kh = (tid & 1) * 8; // X staging role
  const int wk = tid >> 4, wn = (tid & 15) * 8;  // W staging role
  // gate role: row inside my OWN 8-row tile -> xv comes from av[] registers
  const int gr = tx >> 1;                        // which of my 8 rows
  const int gp = (tx & 1) * 2;                   // gate pair: {f,i} or {g,o}

  const size_t rowbase = (size_t)blk * 128;

  float acc[8][8] = {};
  float ga = 0.f, gb = 0.f;

  // -------- prologue: prefetch chunk 0 into registers --------
  float4 xa = *(const float4*)&X[(rowbase + r_st) * 256 + 0 + kh];
  float4 xb = *(const float4*)&X[(rowbase + r_st) * 256 + 0 + kh + 4];
  float4 wa = *(const float4*)&W1[(size_t)(0 + wk) * 128 + wn];
  float4 wb = *(const float4*)&W1[(size_t)(0 + wk) * 128 + wn + 4];
  float wgv = 0.f;
  if (tid < 64) {
    const int kk = tid >> 2, g = tid & 3;
    const float* w = (g == 0) ? Wf : (g == 1) ? Wi : (g == 2) ? Wg : Wo;
    wgv = w[0 + kk];
  }

  for (int kc = 0; kc < 256; kc += BK) {
    __syncthreads();  // previous chunk's reads done before overwrite
    Xs[(kh + 0) * LDX + r_st] = xa.x;
    Xs[(kh + 1) * LDX + r_st] = xa.y;
    Xs[(kh + 2) * LDX + r_st] = xa.z;
    Xs[(kh + 3) * LDX + r_st] = xa.w;
    Xs[(kh + 4) * LDX + r_st] = xb.x;
    Xs[(kh + 5) * LDX + r_st] = xb.y;
    Xs[(kh + 6) * LDX + r_st] = xb.z;
    Xs[(kh + 7) * LDX + r_st] = xb.w;
    *(float4*)&Ws[wk * LDX + wn] = wa;
    *(float4*)&Ws[wk * LDX + wn + 4] = wb;
    if (tid < 64) Wgs[tid] = wgv;
    __syncthreads();

    // -------- prefetch chunk kc+BK (latency hides under compute below) ----
    if (kc + BK < 256) {
      const int kn = kc + BK;
      xa = *(const float4*)&X[(rowbase + r_st) * 256 + kn + kh];
      xb = *(const float4*)&X[(rowbase + r_st) * 256 + kn + kh + 4];
      wa = *(const float4*)&W1[(size_t)(kn + wk) * 128 + wn];
      wb = *(const float4*)&W1[(size_t)(kn + wk) * 128 + wn + 4];
      if (tid < 64) {
        const int kk = tid >> 2, g = tid & 3;
        const float* w = (g == 0) ? Wf : (g == 1) ? Wi : (g == 2) ? Wg : Wo;
        wgv = w[kn + kk];
      }
    }

#pragma unroll
    for (int kk = 0; kk < BK; ++kk) {
      const float4 a0 = *(const float4*)&Xs[kk * LDX + ty * 8];
      const float4 a1 = *(const float4*)&Xs[kk * LDX + ty * 8 + 4];
      const float4 c0 = *(const float4*)&Ws[kk * LDX + tx * 8];
      const float4 c1 = *(const float4*)&Ws[kk * LDX + tx * 8 + 4];
      const float av[8] = {a0.x, a0.y, a0.z, a0.w, a1.x, a1.y, a1.z, a1.w};
      const float bv[8] = {c0.x, c0.y, c0.z, c0.w, c1.x, c1.y, c1.z, c1.w};
#pragma unroll
      for (int i = 0; i < 8; ++i)
#pragma unroll
        for (int j = 0; j < 8; ++j)
          acc[i][j] = fmaf(av[i], bv[j], acc[i][j]);
      // gate dot: xv = X value for row ty*8+gr -> already in av[gr]
      const float xv = av[gr];
      ga = fmaf(xv, Wgs[kk * 4 + gp], ga);
      gb = fmaf(xv, Wgs[kk * 4 + gp + 1], gb);
    }
  }

  float bias[8];
  {
    const float4 u0 = *(const float4*)&b1p[tx * 8];
    const float4 u1 = *(const float4*)&b1p[tx * 8 + 4];
    bias[0] = u0.x; bias[1] = u0.y; bias[2] = u0.z; bias[3] = u0.w;
    bias[4] = u1.x; bias[5] = u1.y; bias[6] = u1.z; bias[7] = u1.w;
  }
#pragma unroll
  for (int i = 0; i < 8; ++i) {
    const size_t row = rowbase + ty * 8 + i;
    float4 o0, o1;
    o0.x = acc[i][0] + bias[0]; o0.y = acc[i][1] + bias[1];
    o0.z = acc[i][2] + bias[2]; o0.w = acc[i][3] + bias[3];
    o1.x = acc[i][4] + bias[4]; o1.y = acc[i][5] + bias[5];
    o1.z = acc[i][6] + bias[6]; o1.w = acc[i][7] + bias[7];
    *(float4*)&PRE[row * PRE_STRIDE + tx * 8] = o0;
    *(float4*)&PRE[row * PRE_STRIDE + tx * 8 + 4] = o1;
  }
  {
    const float ab = (gp == 0) ? bfp[0] : bgp[0];
    const float bb2 = (gp == 0) ? bip[0] : bop[0];
    float2 og;
    og.x = ga + ab; og.y = gb + bb2;
    *(float2*)&PRE[(rowbase + ty * 8 + gr) * PRE_STRIDE + 128 + gp] = og;
  }
}

// ---------------------------------------------------------------------------
// Kernel 3: serial recurrence — R5 version VERBATIM (proven 446 µs).
// R8 post-mortem: global_load_lds staging consumed by the SAME wave with a
// dynamic slot index forces a compiler-inserted s_waitcnt vmcnt(0) before the
// dependent ds_reads (it can't disambiguate LDS slots) -> full HBM latency
// exposed per step (+1100 cy/step, 446->680 µs). Do NOT reintroduce.
// ---------------------------------------------------------------------------
__device__ __forceinline__ float sigmoid_f(float x) {
  return __fdividef(1.0f, 1.0f + __expf(-x));
}
__device__ __forceinline__ float tanh_f(float x) {
  const float e = __expf(-2.0f * x);
  return __fdividef(1.0f - e, 1.0f + e);
}
__device__ __forceinline__ float readlane_f(float v, int lane) {
  return __int_as_float(__builtin_amdgcn_readlane(__float_as_int(v), lane));
}

__global__ __attribute__((amdgpu_waves_per_eu(1, 1))) __launch_bounds__(64)
void rec_kernel(
    const float* __restrict__ PRE, const float* __restrict__ W2,
    const float* __restrict__ b2, const float* __restrict__ aux,
    float* __restrict__ out) {
  __shared__ __align__(16) float h1s[128];

  const int l = threadIdx.x;
  const int b = blockIdx.x;
  const int m = l & 31, half = l >> 5;
  const int g = m >> 3;             // my gate group: 0=f 1=i 2=g 3=o
  const int g8 = g * 8;             // first column of my group

  // W2 fragment in registers: lane (m,half) holds W2[half*64+u][m]
  float w2r[64];
#pragma unroll
  for (int u = 0; u < 64; ++u) w2r[u] = W2[(size_t)(half * 64 + u) * 32 + m];
  // my group's 8 b2 entries (per-lane g -> VGPR loads, 16B aligned)
  const float4 b2a = *(const float4*)&b2[g8];
  const float4 b2b = *(const float4*)&b2[g8 + 4];
  const float2 s1 = *(const float2*)&aux[2 * l];
  const float4 sg = *(const float4*)&aux[128];  // sf, si, sg, so

  float h = 0.f, c = 0.f;

  const float* pr0 = PRE + (size_t)b * PRE_STRIDE;
  const size_t ts = (size_t)BATCH * PRE_STRIDE;

  // depth-2 rotating prefetch
  float2 p0 = *(const float2*)(pr0 + 0 * ts + 2 * l);
  float4 g0 = *(const float4*)(pr0 + 0 * ts + 128);
  float2 p1 = *(const float2*)(pr0 + 1 * ts + 2 * l);
  float4 g1 = *(const float4*)(pr0 + 1 * ts + 128);

  const float4* h1p = (const float4*)&h1s[half * 64];

  for (int t = 0; t < SEQ; ++t) {
    // h1 = relu(pre + h*s1)
    const float h10 = fmaxf(fmaf(h, s1.x, p0.x), 0.f);
    const float h11 = fmaxf(fmaf(h, s1.y, p0.y), 0.f);

    // publish h1 (the step's only LDS write); DS pipe is in-order per wave,
    // so the later ds_reads observe it without an explicit waitcnt.
    ((float2*)h1s)[l] = make_float2(h10, h11);
    asm volatile("" ::: "memory");  // compiler barrier only — no s_waitcnt

    // classical gates — independent VALU work placed to overlap LDS latency
    const float zf = fmaf(h, sg.x, g0.x);
    const float zi = fmaf(h, sg.y, g0.y);
    const float zg = fmaf(h, sg.z, g0.z);
    const float zo = fmaf(h, sg.w, g0.w);
    const float cf = sigmoid_f(zf);
    const float ci = sigmoid_f(zi);
    const float cg = tanh_f(zg);
    const float co = sigmoid_f(zo);
    // rotate prefetch (depth 2)
    p0 = p1; g0 = g1;
    const int tn = (t + 2 < SEQ) ? (t + 2) : (SEQ - 1);
    p1 = *(const float2*)(pr0 + (size_t)tn * ts + 2 * l);
    g1 = *(const float4*)(pr0 + (size_t)tn * ts + 128);

    // partial[m,half] = sum over my K-half of h1[j]*W2[j][m]
    float q0 = 0.f, q1 = 0.f, q2 = 0.f, q3 = 0.f;
#pragma unroll
    for (int jj = 0; jj < 16; ++jj) {
      const float4 hv = h1p[jj];
      q0 = fmaf(hv.x, w2r[4 * jj + 0], q0);
      q1 = fmaf(hv.y, w2r[4 * jj + 1], q1);
      q2 = fmaf(hv.z, w2r[4 * jj + 2], q2);
      q3 = fmaf(hv.w, w2r[4 * jj + 3], q3);
    }
    const float part = (q0 + q1) + (q2 + q3);

    // ONE pipelined 16-shfl burst: both halves' partials for my group's 8 m's
    const float a0 = __shfl(part, g8 + 0, 64), b0 = __shfl(part, 32 + g8 + 0, 64);
    const float a1 = __shfl(part, g8 + 1, 64), b1 = __shfl(part, 32 + g8 + 1, 64);
    const float a2 = __shfl(part, g8 + 2, 64), b2s = __shfl(part, 32 + g8 + 2, 64);
    const float a3 = __shfl(part, g8 + 3, 64), b3 = __shfl(part, 32 + g8 + 3, 64);
    const float a4 = __shfl(part, g8 + 4, 64), b4 = __shfl(part, 32 + g8 + 4, 64);
    const float a5 = __shfl(part, g8 + 5, 64), b5 = __shfl(part, 32 + g8 + 5, 64);
    const float a6 = __shfl(part, g8 + 6, 64), b6 = __shfl(part, 32 + g8 + 6, 64);
    const float a7 = __shfl(part, g8 + 7, 64), b7 = __shfl(part, 32 + g8 + 7, 64);

    // theta + cos, per-lane redundant (every lane evaluates ITS group)
    const float e0 = __cosf(a0 + b0 + b2a.x);
    const float e1 = __cosf(a1 + b1 + b2a.y);
    const float e2 = __cosf(a2 + b2s + b2a.z);
    const float e3 = __cosf(a3 + b3 + b2a.w);
    const float e4 = __cosf(a4 + b4 + b2b.x);
    const float e5 = __cosf(a5 + b5 + b2b.y);
    const float e6 = __cosf(a6 + b6 + b2b.z);
    const float e7 = __cosf(a7 + b7 + b2b.w);
    float p = e0, s = e0;
    p *= e1; s += p;
    p *= e2; s += p;
    p *= e3; s += p;
    p *= e4; s += p;
    p *= e5; s += p;
    p *= e6; s += p;
    p *= e7; s += p;
    const float qv = s * 0.125f;

    // one quantum activation per lane (group 2: tanh = 2*sigmoid(2x)-1)
    const float qarg = (g == 2) ? (2.0f * qv) : qv;
    const float qs = sigmoid_f(qarg);
    const float av = (g == 2) ? (2.0f * qs - 1.0f) : qs;

    // collect the 4 gate scalars via v_readlane (VALU, uniform lane indices)
    const float aF = readlane_f(av, 0);
    const float aI = readlane_f(av, 8);
    const float aG = readlane_f(av, 16);
    const float aO = readlane_f(av, 24);

    const float f  = 0.5f * (cf + aF);
    const float ii = 0.5f * (ci + aI);
    const float gg = 0.5f * (cg + aG);
    const float oo = 0.5f * (co + aO);

    c = fmaf(f, c, ii * gg);
    h = oo * tanh_f(c);

    float4 hv4o; hv4o.x = h; hv4o.y = h; hv4o.z = h; hv4o.w = h;
    *(float4*)(out + ((size_t)t * BATCH + b) * 256 + 4 * l) = hv4o;
  }

  // final (hx, cx)
  float4 hq; hq.x = h; hq.y = h; hq.z = h; hq.w = h;
  float4 cq; cq.x = c; cq.y = c; cq.z = c; cq.w = c;
  *(float4*)(out + (size_t)SEQ * BATCH * 256 + (size_t)b * 256 + 4 * l) = hq;
  *(float4*)(out + (size_t)SEQ * BATCH * 256 + (size_t)BATCH * 256 +
             (size_t)b * 256 + 4 * l) = cq;
}

// ---------------------------------------------------------------------------
extern "C" void kernel_launch(void* const* d_in, const int* in_sizes, int n_in,
                              void* d_out, int out_size, void* d_ws,
                              size_t ws_size, hipStream_t stream) {
  const float* X  = (const float*)d_in[0];
  const float* W1 = (const float*)d_in[1];
  const float* b1 = (const float*)d_in[2];
  const float* W2 = (const float*)d_in[3];
  const float* b2 = (const float*)d_in[4];
  const float* Wf = (const float*)d_in[5];
  const float* bf = (const float*)d_in[6];
  const float* Wi = (const float*)d_in[7];
  const float* bi = (const float*)d_in[8];
  const float* Wg = (const float*)d_in[9];
  const float* bg = (const float*)d_in[10];
  const float* Wo = (const float*)d_in[11];
  const float* bo = (const float*)d_in[12];

  float* ws  = (float*)d_ws;
  float* PRE = ws;
  float* aux = ws + AUX_OFF;
  float* out = (float*)d_out;

  prep_kernel<<<1, 256, 0, stream>>>(W1, Wf, Wi, Wg, Wo, bf, bi, bg, bo, aux);
  gemm_kernel<<<M_ROWS / 128, 256, 0, stream>>>(X, W1, b1, Wf, Wi, Wg, Wo,
                                                bf, bi, bg, bo, PRE);
  rec_kernel<<<BATCH, 64, 0, stream>>>(PRE, W2, b2, aux, out);
}